// Round 5
// baseline (423.094 us; speedup 1.0000x reference)
//
#include <hip/hip_runtime.h>
#include <hip/hip_bf16.h>
#include <math.h>

#define EPS 1e-5f

typedef __attribute__((ext_vector_type(8))) short short8v;   // 8 bf16 (4 VGPR)
typedef __attribute__((ext_vector_type(4))) short short4v;   // 4 bf16
typedef __attribute__((ext_vector_type(4))) float f32x4;

// wave-local LDS fence: compiler ordering + drain ds ops (guide rule 18)
#define WAVE_FENCE() do { asm volatile("s_waitcnt lgkmcnt(0)" ::: "memory"); \
                          __builtin_amdgcn_sched_barrier(0); } while (0)

__device__ __forceinline__ short f2bf(float f) {
    __hip_bfloat16 h = __float2bfloat16(f);
    return *reinterpret_cast<short*>(&h);
}
__device__ __forceinline__ short8v pack8(float4 a, float4 b) {
    short8v r;
    r[0] = f2bf(a.x); r[1] = f2bf(a.y); r[2] = f2bf(a.z); r[3] = f2bf(a.w);
    r[4] = f2bf(b.x); r[5] = f2bf(b.y); r[6] = f2bf(b.z); r[7] = f2bf(b.w);
    return r;
}

// ---------------- prep: convert weights to bf16 (Wsi/Wl zero-padded) ------
__global__ __launch_bounds__(256) void k_prep(
    const float* __restrict__ Ws, const float* __restrict__ Wsi,
    const float* __restrict__ Wl, const float* __restrict__ Wd,
    short* __restrict__ wsb, short* __restrict__ wsib, short* __restrict__ wlb,
    short* __restrict__ wdb)
{
    int i = blockIdx.x * 256 + threadIdx.x;
    if (i < 128 * 64) wsb[i] = f2bf(Ws[i]);
    if (i < 32 * 32) { int p = i >> 5, n = i & 31; wsib[i] = (n < 26) ? f2bf(Wsi[p * 26 + n]) : (short)0; }
    if (i < 128 * 256) wdb[i] = f2bf(Wd[i]);
    if (i < 512 * 544) { int c = i / 544, k = i - c * 544; wlb[i] = (k < 528) ? f2bf(Wl[c * 528 + k]) : (short)0; }
}

// ---------------- Kernel 1: xbf = LN(dense @ Wd^T) via MFMA, bf16 out ----
__global__ __launch_bounds__(256) void k_dense_ln(
    const float* __restrict__ dense, const short* __restrict__ wdb,
    const float* __restrict__ gd, const float* __restrict__ bd,
    short* __restrict__ xbf)
{
    __shared__ float red[4][32][2];
    __shared__ float minv[32][2];
    const int t = threadIdx.x;
    const int wv = t >> 6, l = t & 63;
    const int g = l >> 4, c = l & 15;
    const size_t r0 = (size_t)blockIdx.x * 32;

    f32x4 acc[2][2];
    #pragma unroll
    for (int mt = 0; mt < 2; ++mt)
        #pragma unroll
        for (int nt = 0; nt < 2; ++nt) acc[mt][nt] = (f32x4){0.f, 0.f, 0.f, 0.f};

    #pragma unroll
    for (int ks = 0; ks < 8; ++ks) {
        short8v b0 = *(const short8v*)(wdb + (wv * 32 + c) * 256 + ks * 32 + g * 8);
        short8v b1 = *(const short8v*)(wdb + (wv * 32 + 16 + c) * 256 + ks * 32 + g * 8);
        #pragma unroll
        for (int mt = 0; mt < 2; ++mt) {
            const float* p = dense + (r0 + mt * 16 + c) * 256 + ks * 32 + g * 8;
            short8v a = pack8(*(const float4*)p, *(const float4*)(p + 4));
            acc[mt][0] = __builtin_amdgcn_mfma_f32_16x16x32_bf16(a, b0, acc[mt][0], 0, 0, 0);
            acc[mt][1] = __builtin_amdgcn_mfma_f32_16x16x32_bf16(a, b1, acc[mt][1], 0, 0, 0);
        }
    }
    #pragma unroll
    for (int mt = 0; mt < 2; ++mt)
        #pragma unroll
        for (int reg = 0; reg < 4; ++reg) {
            float v0 = acc[mt][0][reg], v1 = acc[mt][1][reg];
            float s = v0 + v1, q = v0 * v0 + v1 * v1;
            s += __shfl_xor(s, 1); q += __shfl_xor(q, 1);
            s += __shfl_xor(s, 2); q += __shfl_xor(q, 2);
            s += __shfl_xor(s, 4); q += __shfl_xor(q, 4);
            s += __shfl_xor(s, 8); q += __shfl_xor(q, 8);
            if (c == 0) {
                red[wv][mt * 16 + g * 4 + reg][0] = s;
                red[wv][mt * 16 + g * 4 + reg][1] = q;
            }
        }
    __syncthreads();
    if (t < 32) {
        float S = red[0][t][0] + red[1][t][0] + red[2][t][0] + red[3][t][0];
        float Q = red[0][t][1] + red[1][t][1] + red[2][t][1] + red[3][t][1];
        float m = S * (1.f / 128.f);
        float v = Q * (1.f / 128.f) - m * m;
        minv[t][0] = m; minv[t][1] = rsqrtf(v + EPS);
    }
    __syncthreads();
    const float ge0 = gd[wv * 32 + c],      be0 = bd[wv * 32 + c];
    const float ge1 = gd[wv * 32 + 16 + c], be1 = bd[wv * 32 + 16 + c];
    #pragma unroll
    for (int mt = 0; mt < 2; ++mt)
        #pragma unroll
        for (int reg = 0; reg < 4; ++reg) {
            int rr = mt * 16 + g * 4 + reg;
            float m = minv[rr][0], inv = minv[rr][1];
            xbf[(r0 + rr) * 128 + wv * 32 + c]      = f2bf((acc[mt][0][reg] - m) * inv * ge0 + be0);
            xbf[(r0 + rr) * 128 + wv * 32 + 16 + c] = f2bf((acc[mt][1][reg] - m) * inv * ge1 + be1);
        }
}

// ---------------- Kernel 2: fused middle -> Zflat (wave-independent) ------
// 4 rows / block = 1 row per wave; NO block barriers (wave-local fences only).
__global__ __launch_bounds__(256) void k_middle(
    const float* __restrict__ sparse, const short* __restrict__ Wsb,
    const float* __restrict__ gs, const float* __restrict__ bs,
    const short* __restrict__ Wsib, const float* __restrict__ gsi, const float* __restrict__ bsi,
    const short* __restrict__ xbf, short* __restrict__ zf)
{
    __shared__ __align__(16) short lds[4][4224];    // 33792 B total
    const int t = threadIdx.x;
    const int w = t >> 6, l = t & 63;
    const int g = l >> 4, c = l & 15;
    const size_t row = (size_t)blockIdx.x * 4 + w;
    short* W = &lds[w][0];

    // ---- stage A: own-row y1pre = sparse_row @ Ws^T  (M=32n, N=128e, K=64) ----
    short8v afr[2][2];
    #pragma unroll
    for (int mt = 0; mt < 2; ++mt) {
        const int n = mt * 16 + c;
        #pragma unroll
        for (int ks = 0; ks < 2; ++ks) {
            if (n < 26) {
                const float* p = sparse + row * 1664 + n * 64 + ks * 32 + g * 8;
                afr[mt][ks] = pack8(*(const float4*)p, *(const float4*)(p + 4));
            } else {
                afr[mt][ks] = (short8v){0, 0, 0, 0, 0, 0, 0, 0};
            }
        }
    }
    f32x4 acc[2][8];
    #pragma unroll
    for (int mt = 0; mt < 2; ++mt)
        #pragma unroll
        for (int nt = 0; nt < 8; ++nt) acc[mt][nt] = (f32x4){0.f, 0.f, 0.f, 0.f};
    #pragma unroll
    for (int nt = 0; nt < 8; ++nt) {
        short8v b0 = *(const short8v*)(Wsb + (nt * 16 + c) * 64 + g * 8);
        short8v b1 = *(const short8v*)(Wsb + (nt * 16 + c) * 64 + 32 + g * 8);
        #pragma unroll
        for (int mt = 0; mt < 2; ++mt) {
            acc[mt][nt] = __builtin_amdgcn_mfma_f32_16x16x32_bf16(afr[mt][0], b0, acc[mt][nt], 0, 0, 0);
            acc[mt][nt] = __builtin_amdgcn_mfma_f32_16x16x32_bf16(afr[mt][1], b1, acc[mt][nt], 0, 0, 0);
        }
    }
    // ---- LN over e=128, entirely in-wave ----
    float ge[8], be[8];
    #pragma unroll
    for (int nt = 0; nt < 8; ++nt) { ge[nt] = gs[nt * 16 + c]; be[nt] = bs[nt * 16 + c]; }
    float m_[2][4], inv_[2][4];
    #pragma unroll
    for (int mt = 0; mt < 2; ++mt)
        #pragma unroll
        for (int reg = 0; reg < 4; ++reg) {
            float s = 0.f, q = 0.f;
            #pragma unroll
            for (int nt = 0; nt < 8; ++nt) { float v = acc[mt][nt][reg]; s += v; q += v * v; }
            s += __shfl_xor(s, 1); q += __shfl_xor(q, 1);
            s += __shfl_xor(s, 2); q += __shfl_xor(q, 2);
            s += __shfl_xor(s, 4); q += __shfl_xor(q, 4);
            s += __shfl_xor(s, 8); q += __shfl_xor(q, 8);
            float m = s * (1.f / 128.f);
            float v = q * (1.f / 128.f) - m * m;
            m_[mt][reg] = m; inv_[mt][reg] = rsqrtf(v + EPS);
        }
    // ---- write y1t[e][n] (bf16, 64B rows, granule swizzle gi ^= (e>>1)&3) ----
    #pragma unroll
    for (int mt = 0; mt < 2; ++mt)
        #pragma unroll
        for (int nt = 0; nt < 8; ++nt) {
            short4v y;
            #pragma unroll
            for (int reg = 0; reg < 4; ++reg) {
                int n = mt * 16 + g * 4 + reg;
                float val = (n < 26) ? ((acc[mt][nt][reg] - m_[mt][reg]) * inv_[mt][reg] * ge[nt] + be[nt]) : 0.f;
                y[reg] = f2bf(val);
            }
            int e = nt * 16 + c;
            int gi = 2 * mt + (g >> 1);
            int off = e * 32 + ((gi ^ ((e >> 1) & 3)) << 3) + (g & 1) * 4;
            *(short4v*)(W + off) = y;
        }
    WAVE_FENCE();                        // y1t writes -> stage-B reads (wave-local)

    // ---- stage B: y2 = y1^T @ Wsi^T + LN(p=32) -> registers ----
    short8v bwsi0 = *(const short8v*)(Wsib + c * 32 + g * 8);
    short8v bwsi1 = *(const short8v*)(Wsib + (16 + c) * 32 + g * 8);
    const float gA = gsi[c], bA = bsi[c];
    const float gB = gsi[16 + c], bB = bsi[16 + c];
    short4v tvA[8], tvB[8];
    #pragma unroll
    for (int mt = 0; mt < 8; ++mt) {
        int e = mt * 16 + c;
        short8v af = *(const short8v*)(W + e * 32 + ((g ^ ((e >> 1) & 3)) << 3));
        f32x4 c0 = (f32x4){0, 0, 0, 0}, c1 = (f32x4){0, 0, 0, 0};
        c0 = __builtin_amdgcn_mfma_f32_16x16x32_bf16(af, bwsi0, c0, 0, 0, 0);
        c1 = __builtin_amdgcn_mfma_f32_16x16x32_bf16(af, bwsi1, c1, 0, 0, 0);
        #pragma unroll
        for (int reg = 0; reg < 4; ++reg) {
            float v0 = c0[reg], v1 = c1[reg];
            float s = v0 + v1, q = v0 * v0 + v1 * v1;
            s += __shfl_xor(s, 1); q += __shfl_xor(q, 1);
            s += __shfl_xor(s, 2); q += __shfl_xor(q, 2);
            s += __shfl_xor(s, 4); q += __shfl_xor(q, 4);
            s += __shfl_xor(s, 8); q += __shfl_xor(q, 8);
            float m = s * (1.f / 32.f);
            float var = q * (1.f / 32.f) - m * m;
            float inv = rsqrtf(var + EPS);
            tvA[mt][reg] = f2bf((v0 - m) * inv * gA + bA);
            tvB[mt][reg] = f2bf((v1 - m) * inv * gB + bB);
        }
    }
    WAVE_FENCE();                        // stage-B reads done -> T may overlay (WAR)

    // ---- build T = [x ; y2^T] (256B rows, swizzle d ^= (i&7)<<3 in shorts) ----
    if (l < 16) *(short8v*)(W + l * 8) = *(const short8v*)(xbf + row * 128 + l * 8);
    #pragma unroll
    for (int mt = 0; mt < 8; ++mt) {
        { int i = 1 + c;  *(short4v*)(W + i * 128 + ((mt * 16 + g * 4) ^ ((i & 7) << 3))) = tvA[mt]; }
        { int i = 17 + c; *(short4v*)(W + i * 128 + ((mt * 16 + g * 4) ^ ((i & 7) << 3))) = tvB[mt]; }
    }
    WAVE_FENCE();                        // T writes -> gram reads (wave-local)

    // ---- strict-lower gram via MFMA (A/B frags of T coincide) ----
    f32x4 z00 = (f32x4){0,0,0,0}, z10 = (f32x4){0,0,0,0}, z11 = (f32x4){0,0,0,0};
    f32x4 z20 = (f32x4){0,0,0,0}, z21 = (f32x4){0,0,0,0};
    #pragma unroll
    for (int ks = 0; ks < 4; ++ks) {
        int d = ks * 32 + g * 8;
        short8v f0 = *(const short8v*)(W + c * 128 + (d ^ ((c & 7) << 3)));
        short8v f1 = *(const short8v*)(W + (16 + c) * 128 + (d ^ ((c & 7) << 3)));
        short8v f2 = *(const short8v*)(W + 32 * 128 + d);
        z00 = __builtin_amdgcn_mfma_f32_16x16x32_bf16(f0, f0, z00, 0, 0, 0);
        z10 = __builtin_amdgcn_mfma_f32_16x16x32_bf16(f1, f0, z10, 0, 0, 0);
        z11 = __builtin_amdgcn_mfma_f32_16x16x32_bf16(f1, f1, z11, 0, 0, 0);
        z20 = __builtin_amdgcn_mfma_f32_16x16x32_bf16(f2, f0, z20, 0, 0, 0);
        z21 = __builtin_amdgcn_mfma_f32_16x16x32_bf16(f2, f1, z21, 0, 0, 0);
    }
    short* zr = zf + row * 544;
    #pragma unroll
    for (int reg = 0; reg < 4; ++reg) {
        int i0 = g * 4 + reg;
        { int i = i0;      int j = c;      if (j < i)  zr[i * (i - 1) / 2 + j] = f2bf(z00[reg]); }
        { int i = 16 + i0; int j = c;                  zr[i * (i - 1) / 2 + j] = f2bf(z10[reg]); }
        { int i = 16 + i0; int j = 16 + c; if (j < i)  zr[i * (i - 1) / 2 + j] = f2bf(z11[reg]); }
        { int i = 32 + i0; int j = c;      if (i < 33) zr[i * (i - 1) / 2 + j] = f2bf(z20[reg]); }
        { int i = 32 + i0; int j = 16 + c; if (i < 33) zr[i * (i - 1) / 2 + j] = f2bf(z21[reg]); }
    }
    if (l < 16) zr[528 + l] = 0;   // zero the K-pad for k_final
}

// ---------------- Kernel 3: out = mask * LN(Zflat @ Wl^T) via MFMA --------
// 32 rows x 512 cols per block, 512 threads (8 waves: 2M x 4N).
// Wl chunk reg-prefetch: load ks+1 while MFMAing ks.
__global__ __launch_bounds__(512) void k_final(
    const short* __restrict__ zf, const short* __restrict__ Wlb,
    const float* __restrict__ gl, const float* __restrict__ bl,
    const int* __restrict__ dims_p, float* __restrict__ out)
{
    __shared__ __align__(16) short zlds[32][552];   // 35328 B (all K at once)
    __shared__ __align__(16) short wlds[512][40];   // 40960 B (one 32-K chunk)
    __shared__ float red[32][4][2];                 //  1024 B
    const int t = threadIdx.x;
    const int wv = t >> 6;
    const int l = t & 63;
    const int g = l >> 4, c = l & 15;
    const int wm = wv >> 2;        // 0..1: row half
    const int wn = wv & 3;         // 0..3: col quarter
    const size_t r0 = (size_t)blockIdx.x * 32;

    for (int f = t; f < 32 * 68; f += 512) {
        int r = f / 68, s = f - r * 68;
        *(short8v*)(&zlds[r][s * 8]) = *(const short8v*)(zf + (r0 + r) * 544 + s * 8);
    }
    short8v wreg[4];
    #pragma unroll
    for (int j = 0; j < 4; ++j) {
        int f = t + j * 512, cc = f >> 2, part = f & 3;
        wreg[j] = *(const short8v*)(Wlb + cc * 544 + part * 8);
    }
    f32x4 acc[8];
    #pragma unroll
    for (int i = 0; i < 8; ++i) acc[i] = (f32x4){0, 0, 0, 0};
    for (int ks = 0; ks < 17; ++ks) {
        __syncthreads();                            // prev-iter wlds reads done
        #pragma unroll
        for (int j = 0; j < 4; ++j) {
            int f = t + j * 512, cc = f >> 2, part = f & 3;
            *(short8v*)(&wlds[cc][part * 8]) = wreg[j];
        }
        if (ks < 16) {
            #pragma unroll
            for (int j = 0; j < 4; ++j) {
                int f = t + j * 512, cc = f >> 2, part = f & 3;
                wreg[j] = *(const short8v*)(Wlb + cc * 544 + (ks + 1) * 32 + part * 8);
            }
        }
        __syncthreads();
        short8v af = *(const short8v*)(&zlds[wm * 16 + c][ks * 32 + g * 8]);
        #pragma unroll
        for (int nt = 0; nt < 8; ++nt) {
            short8v bf = *(const short8v*)(&wlds[wn * 128 + nt * 16 + c][g * 8]);
            acc[nt] = __builtin_amdgcn_mfma_f32_16x16x32_bf16(af, bf, acc[nt], 0, 0, 0);
        }
    }
    // LN epilogue over 512 cols per row
    #pragma unroll
    for (int reg = 0; reg < 4; ++reg) {
        float s = 0.f, q = 0.f;
        #pragma unroll
        for (int nt = 0; nt < 8; ++nt) { float v = acc[nt][reg]; s += v; q += v * v; }
        s += __shfl_xor(s, 1); q += __shfl_xor(q, 1);
        s += __shfl_xor(s, 2); q += __shfl_xor(q, 2);
        s += __shfl_xor(s, 4); q += __shfl_xor(q, 4);
        s += __shfl_xor(s, 8); q += __shfl_xor(q, 8);
        if (c == 0) { red[wm * 16 + g * 4 + reg][wn][0] = s; red[wm * 16 + g * 4 + reg][wn][1] = q; }
    }
    __syncthreads();
    const int dims = dims_p[0];
    float M[4], INV[4];
    #pragma unroll
    for (int reg = 0; reg < 4; ++reg) {
        int rr = wm * 16 + g * 4 + reg;
        float S = red[rr][0][0] + red[rr][1][0] + red[rr][2][0] + red[rr][3][0];
        float Q = red[rr][0][1] + red[rr][1][1] + red[rr][2][1] + red[rr][3][1];
        float m = S * (1.f / 512.f);
        float v = Q * (1.f / 512.f) - m * m;
        M[reg] = m; INV[reg] = rsqrtf(v + EPS);
    }
    #pragma unroll
    for (int nt = 0; nt < 8; ++nt) {
        int cc = wn * 128 + nt * 16 + c;
        float gg = (cc < dims) ? gl[cc] : 0.f;
        float bb = (cc < dims) ? bl[cc] : 0.f;
        #pragma unroll
        for (int reg = 0; reg < 4; ++reg) {
            int rr = wm * 16 + g * 4 + reg;
            out[(r0 + rr) * 512 + cc] = (acc[nt][reg] - M[reg]) * INV[reg] * gg + bb;
        }
    }
}

extern "C" void kernel_launch(void* const* d_in, const int* in_sizes, int n_in,
                              void* d_out, int out_size, void* d_ws, size_t ws_size,
                              hipStream_t stream)
{
    const float* dense  = (const float*)d_in[0];
    const float* sparse = (const float*)d_in[1];
    const float* Wd  = (const float*)d_in[2];
    const float* gd  = (const float*)d_in[3];
    const float* bd  = (const float*)d_in[4];
    const float* Ws  = (const float*)d_in[5];
    const float* gs  = (const float*)d_in[6];
    const float* bs  = (const float*)d_in[7];
    const float* Wsi = (const float*)d_in[8];
    const float* gsi = (const float*)d_in[9];
    const float* bsi = (const float*)d_in[10];
    const float* Wl  = (const float*)d_in[11];
    const float* gl  = (const float*)d_in[12];
    const float* bl  = (const float*)d_in[13];
    const int*   dims = (const int*)d_in[14];
    float* out = (float*)d_out;
    (void)n_in; (void)out_size; (void)ws_size;

    const int B = in_sizes[0] / 256;                    // 32768
    short* xbf = (short*)d_ws;                                         // B*128*2
    short* zfw = xbf + (size_t)B * 128;                                // B*544*2
    short* wsb = zfw + (size_t)B * 544;                                // 16384 B
    short* wsib = wsb + 128 * 64;                                      // 2048 B
    short* wlb  = wsib + 32 * 32;                                      // 557056 B
    short* wdb  = wlb + 512 * 544;                                     // 65536 B

    hipLaunchKernelGGL(k_prep, dim3(1088), dim3(256), 0, stream,
                       Ws, Wsi, Wl, Wd, wsb, wsib, wlb, wdb);
    hipLaunchKernelGGL(k_dense_ln, dim3(B / 32), dim3(256), 0, stream,
                       dense, wdb, gd, bd, xbf);
    hipLaunchKernelGGL(k_middle, dim3(B / 4), dim3(256), 0, stream,
                       sparse, wsb, gs, bs, wsib, gsi, bsi, xbf, zfw);
    hipLaunchKernelGGL(k_final, dim3(B / 32), dim3(512), 0, stream,
                       zfw, wlb, gl, bl, dims, out);
}

// Round 6
// 215.710 us; speedup vs baseline: 1.9614x; 1.9614x over previous
//
#include <hip/hip_runtime.h>
#include <hip/hip_bf16.h>
#include <math.h>

#define EPS 1e-5f

typedef __attribute__((ext_vector_type(8))) short short8v;   // 8 bf16 (4 VGPR)
typedef __attribute__((ext_vector_type(4))) short short4v;   // 4 bf16
typedef __attribute__((ext_vector_type(4))) float f32x4;

__device__ __forceinline__ short f2bf(float f) {
    union { float f; unsigned u; } v; v.f = f;
    unsigned r = v.u + 0x7FFFu + ((v.u >> 16) & 1u);
    return (short)(r >> 16);
}
__device__ __forceinline__ short8v pack8(float4 a, float4 b) {
    short8v r;
    r[0] = f2bf(a.x); r[1] = f2bf(a.y); r[2] = f2bf(a.z); r[3] = f2bf(a.w);
    r[4] = f2bf(b.x); r[5] = f2bf(b.y); r[6] = f2bf(b.z); r[7] = f2bf(b.w);
    return r;
}

// ---------------- prep: convert weights to bf16 (Wsi/Wl zero-padded) ------
__global__ __launch_bounds__(256) void k_prep(
    const float* __restrict__ Ws, const float* __restrict__ Wsi,
    const float* __restrict__ Wl, const float* __restrict__ Wd,
    short* __restrict__ wsb, short* __restrict__ wsib, short* __restrict__ wlb,
    short* __restrict__ wdb)
{
    int i = blockIdx.x * 256 + threadIdx.x;
    if (i < 128 * 64) wsb[i] = f2bf(Ws[i]);
    if (i < 32 * 32) { int p = i >> 5, n = i & 31; wsib[i] = (n < 26) ? f2bf(Wsi[p * 26 + n]) : (short)0; }
    if (i < 128 * 256) wdb[i] = f2bf(Wd[i]);
    if (i < 512 * 544) { int c = i / 544, k = i - c * 544; wlb[i] = (k < 528) ? f2bf(Wl[c * 528 + k]) : (short)0; }
}

// ---------------- Kernel 1: xbf = LN(dense @ Wd^T) via MFMA, bf16 out ----
__global__ __launch_bounds__(256) void k_dense_ln(
    const float* __restrict__ dense, const short* __restrict__ wdb,
    const float* __restrict__ gd, const float* __restrict__ bd,
    short* __restrict__ xbf)
{
    __shared__ float red[4][32][2];
    __shared__ float minv[32][2];
    const int t = threadIdx.x;
    const int wv = t >> 6, l = t & 63;
    const int g = l >> 4, c = l & 15;
    const size_t r0 = (size_t)blockIdx.x * 32;

    f32x4 acc[2][2];
    #pragma unroll
    for (int mt = 0; mt < 2; ++mt)
        #pragma unroll
        for (int nt = 0; nt < 2; ++nt) acc[mt][nt] = (f32x4){0.f, 0.f, 0.f, 0.f};

    #pragma unroll
    for (int ks = 0; ks < 8; ++ks) {
        short8v b0 = *(const short8v*)(wdb + (wv * 32 + c) * 256 + ks * 32 + g * 8);
        short8v b1 = *(const short8v*)(wdb + (wv * 32 + 16 + c) * 256 + ks * 32 + g * 8);
        #pragma unroll
        for (int mt = 0; mt < 2; ++mt) {
            const float* p = dense + (r0 + mt * 16 + c) * 256 + ks * 32 + g * 8;
            short8v a = pack8(*(const float4*)p, *(const float4*)(p + 4));
            acc[mt][0] = __builtin_amdgcn_mfma_f32_16x16x32_bf16(a, b0, acc[mt][0], 0, 0, 0);
            acc[mt][1] = __builtin_amdgcn_mfma_f32_16x16x32_bf16(a, b1, acc[mt][1], 0, 0, 0);
        }
    }
    #pragma unroll
    for (int mt = 0; mt < 2; ++mt)
        #pragma unroll
        for (int reg = 0; reg < 4; ++reg) {
            float v0 = acc[mt][0][reg], v1 = acc[mt][1][reg];
            float s = v0 + v1, q = v0 * v0 + v1 * v1;
            s += __shfl_xor(s, 1); q += __shfl_xor(q, 1);
            s += __shfl_xor(s, 2); q += __shfl_xor(q, 2);
            s += __shfl_xor(s, 4); q += __shfl_xor(q, 4);
            s += __shfl_xor(s, 8); q += __shfl_xor(q, 8);
            if (c == 0) {
                red[wv][mt * 16 + g * 4 + reg][0] = s;
                red[wv][mt * 16 + g * 4 + reg][1] = q;
            }
        }
    __syncthreads();
    if (t < 32) {
        float S = red[0][t][0] + red[1][t][0] + red[2][t][0] + red[3][t][0];
        float Q = red[0][t][1] + red[1][t][1] + red[2][t][1] + red[3][t][1];
        float m = S * (1.f / 128.f);
        float v = Q * (1.f / 128.f) - m * m;
        minv[t][0] = m; minv[t][1] = rsqrtf(v + EPS);
    }
    __syncthreads();
    const float ge0 = gd[wv * 32 + c],      be0 = bd[wv * 32 + c];
    const float ge1 = gd[wv * 32 + 16 + c], be1 = bd[wv * 32 + 16 + c];
    #pragma unroll
    for (int mt = 0; mt < 2; ++mt)
        #pragma unroll
        for (int reg = 0; reg < 4; ++reg) {
            int rr = mt * 16 + g * 4 + reg;
            float m = minv[rr][0], inv = minv[rr][1];
            xbf[(r0 + rr) * 128 + wv * 32 + c]      = f2bf((acc[mt][0][reg] - m) * inv * ge0 + be0);
            xbf[(r0 + rr) * 128 + wv * 32 + 16 + c] = f2bf((acc[mt][1][reg] - m) * inv * ge1 + be1);
        }
}

// ---------------- Kernel 2: fused middle -> Zflat ------------------------
// ONE wave per block, one batch row per wave. __syncthreads() = free
// wave-local fence (no cross-wave lockstep, exact compiler semantics).
__global__ __launch_bounds__(64, 4) void k_middle(
    const float* __restrict__ sparse, const short* __restrict__ Wsb,
    const float* __restrict__ gs, const float* __restrict__ bs,
    const short* __restrict__ Wsib, const float* __restrict__ gsi, const float* __restrict__ bsi,
    const short* __restrict__ xbf, short* __restrict__ zf)
{
    __shared__ __align__(16) short W[4224];    // 8448 B: y1t[128][32] then T[33][128] overlay
    const int l = threadIdx.x;
    const int g = l >> 4;            // lane group
    const int c = l & 15;            // lane-in-group
    const size_t row = (size_t)blockIdx.x;

    // ---- stage A: y1pre = sparse_row @ Ws^T  (M=32n, N=128e, K=64) ----
    short8v afr[2][2];
    #pragma unroll
    for (int mt = 0; mt < 2; ++mt) {
        const int n = mt * 16 + c;
        #pragma unroll
        for (int ks = 0; ks < 2; ++ks) {
            if (n < 26) {
                const float* p = sparse + row * 1664 + n * 64 + ks * 32 + g * 8;
                afr[mt][ks] = pack8(*(const float4*)p, *(const float4*)(p + 4));
            } else {
                afr[mt][ks] = (short8v){0, 0, 0, 0, 0, 0, 0, 0};
            }
        }
    }
    // x row for T[0], loaded early (hides latency under stage A)
    short8v xrow = *(const short8v*)(xbf + row * 128 + (l & 15) * 8);

    f32x4 acc[2][8];
    #pragma unroll
    for (int mt = 0; mt < 2; ++mt)
        #pragma unroll
        for (int nt = 0; nt < 8; ++nt) acc[mt][nt] = (f32x4){0.f, 0.f, 0.f, 0.f};
    #pragma unroll
    for (int nt = 0; nt < 8; ++nt) {
        short8v b0 = *(const short8v*)(Wsb + (nt * 16 + c) * 64 + g * 8);
        short8v b1 = *(const short8v*)(Wsb + (nt * 16 + c) * 64 + 32 + g * 8);
        #pragma unroll
        for (int mt = 0; mt < 2; ++mt) {
            acc[mt][nt] = __builtin_amdgcn_mfma_f32_16x16x32_bf16(afr[mt][0], b0, acc[mt][nt], 0, 0, 0);
            acc[mt][nt] = __builtin_amdgcn_mfma_f32_16x16x32_bf16(afr[mt][1], b1, acc[mt][nt], 0, 0, 0);
        }
    }
    // ---- LN over e=128, in-wave (nt-sum + 5-step c-butterfly) ----
    float m_[2][4], inv_[2][4];
    #pragma unroll
    for (int mt = 0; mt < 2; ++mt)
        #pragma unroll
        for (int reg = 0; reg < 4; ++reg) {
            float s = 0.f, q = 0.f;
            #pragma unroll
            for (int nt = 0; nt < 8; ++nt) { float v = acc[mt][nt][reg]; s += v; q += v * v; }
            s += __shfl_xor(s, 1); q += __shfl_xor(q, 1);
            s += __shfl_xor(s, 2); q += __shfl_xor(q, 2);
            s += __shfl_xor(s, 4); q += __shfl_xor(q, 4);
            s += __shfl_xor(s, 8); q += __shfl_xor(q, 8);
            float m = s * (1.f / 128.f);
            float v = q * (1.f / 128.f) - m * m;
            m_[mt][reg] = m; inv_[mt][reg] = rsqrtf(v + EPS);
        }
    // ---- write y1t[e][n] (64B rows, granule swizzle gi ^= (e>>1)&3) ----
    #pragma unroll
    for (int mt = 0; mt < 2; ++mt)
        #pragma unroll
        for (int nt = 0; nt < 8; ++nt) {
            float ge = gs[nt * 16 + c], be = bs[nt * 16 + c];
            short4v y;
            #pragma unroll
            for (int reg = 0; reg < 4; ++reg) {
                int n = mt * 16 + g * 4 + reg;
                float val = (n < 26) ? ((acc[mt][nt][reg] - m_[mt][reg]) * inv_[mt][reg] * ge + be) : 0.f;
                y[reg] = f2bf(val);
            }
            int e = nt * 16 + c;
            int gi = 2 * mt + (g >> 1);
            int off = e * 32 + ((gi ^ ((e >> 1) & 3)) << 3) + (g & 1) * 4;
            *(short4v*)(W + off) = y;
        }
    __syncthreads();                     // y1t writes -> stage-B reads (1-wave: free)

    // ---- stage B (operand-swapped): y2[p][e] = mfma(Wsi, y1t) ----
    // D[row=p][col=e]: lane holds p = g*4+reg (c0) and 16+g*4+reg (c1), e = mt*16+c.
    short8v awsi0 = *(const short8v*)(Wsib + c * 32 + g * 8);          // A: Wsi[p=c][n]
    short8v awsi1 = *(const short8v*)(Wsib + (16 + c) * 32 + g * 8);   // A: Wsi[p=16+c][n]
    float gsiA[4], bsiA[4], gsiB[4], bsiB[4];
    #pragma unroll
    for (int reg = 0; reg < 4; ++reg) {
        gsiA[reg] = gsi[g * 4 + reg];      bsiA[reg] = bsi[g * 4 + reg];
        gsiB[reg] = gsi[16 + g * 4 + reg]; bsiB[reg] = bsi[16 + g * 4 + reg];
    }
    short8v tv[8];                        // per mt: 8 normalized bf16 p-values
    #pragma unroll
    for (int mt = 0; mt < 8; ++mt) {
        int e = mt * 16 + c;
        short8v bf = *(const short8v*)(W + e * 32 + ((g ^ ((e >> 1) & 3)) << 3));
        f32x4 c0 = (f32x4){0, 0, 0, 0}, c1 = (f32x4){0, 0, 0, 0};
        c0 = __builtin_amdgcn_mfma_f32_16x16x32_bf16(awsi0, bf, c0, 0, 0, 0);
        c1 = __builtin_amdgcn_mfma_f32_16x16x32_bf16(awsi1, bf, c1, 0, 0, 0);
        // LN over p=32 for this lane's e: 8 in-reg + reduce over g (2 shfl x2)
        float s = 0.f, q = 0.f;
        #pragma unroll
        for (int reg = 0; reg < 4; ++reg) {
            float v0 = c0[reg], v1 = c1[reg];
            s += v0 + v1; q += v0 * v0 + v1 * v1;
        }
        s += __shfl_xor(s, 16); q += __shfl_xor(q, 16);
        s += __shfl_xor(s, 32); q += __shfl_xor(q, 32);
        float m = s * (1.f / 32.f);
        float var = q * (1.f / 32.f) - m * m;
        float inv = rsqrtf(var + EPS);
        #pragma unroll
        for (int reg = 0; reg < 4; ++reg) {
            tv[mt][reg]     = f2bf((c0[reg] - m) * inv * gsiA[reg] + bsiA[reg]);
            tv[mt][4 + reg] = f2bf((c1[reg] - m) * inv * gsiB[reg] + bsiB[reg]);
        }
    }
    __syncthreads();                     // stage-B reads done -> T may overlay (WAR)

    // ---- build T = [x ; y2^T] (256B rows, swizzle d ^= (i&7)<<3) ----
    if (l < 16) *(short8v*)(W + l * 8) = xrow;
    #pragma unroll
    for (int mt = 0; mt < 8; ++mt) {
        int d = mt * 16 + c;
        #pragma unroll
        for (int reg = 0; reg < 4; ++reg) {
            int i0 = 1 + g * 4 + reg;
            int i1 = 17 + g * 4 + reg;
            W[i0 * 128 + (d ^ ((i0 & 7) << 3))] = tv[mt][reg];
            W[i1 * 128 + (d ^ ((i1 & 7) << 3))] = tv[mt][4 + reg];
        }
    }
    __syncthreads();                     // T writes -> gram reads

    // ---- strict-lower gram via MFMA (A/B frags of T coincide) ----
    f32x4 z00 = (f32x4){0,0,0,0}, z10 = (f32x4){0,0,0,0}, z11 = (f32x4){0,0,0,0};
    f32x4 z20 = (f32x4){0,0,0,0}, z21 = (f32x4){0,0,0,0};
    #pragma unroll
    for (int ks = 0; ks < 4; ++ks) {
        int d = ks * 32 + g * 8;
        short8v f0 = *(const short8v*)(W + c * 128 + (d ^ ((c & 7) << 3)));
        short8v f1 = *(const short8v*)(W + (16 + c) * 128 + (d ^ ((c & 7) << 3)));
        short8v f2 = *(const short8v*)(W + 32 * 128 + d);
        z00 = __builtin_amdgcn_mfma_f32_16x16x32_bf16(f0, f0, z00, 0, 0, 0);
        z10 = __builtin_amdgcn_mfma_f32_16x16x32_bf16(f1, f0, z10, 0, 0, 0);
        z11 = __builtin_amdgcn_mfma_f32_16x16x32_bf16(f1, f1, z11, 0, 0, 0);
        z20 = __builtin_amdgcn_mfma_f32_16x16x32_bf16(f2, f0, z20, 0, 0, 0);
        z21 = __builtin_amdgcn_mfma_f32_16x16x32_bf16(f2, f1, z21, 0, 0, 0);
    }
    short* zr = zf + row * 544;
    #pragma unroll
    for (int reg = 0; reg < 4; ++reg) {
        int i0 = g * 4 + reg;
        { int i = i0;      int j = c;      if (j < i)  zr[i * (i - 1) / 2 + j] = f2bf(z00[reg]); }
        { int i = 16 + i0; int j = c;                  zr[i * (i - 1) / 2 + j] = f2bf(z10[reg]); }
        { int i = 16 + i0; int j = 16 + c; if (j < i)  zr[i * (i - 1) / 2 + j] = f2bf(z11[reg]); }
        { int i = 32 + i0; int j = c;      if (i < 33) zr[i * (i - 1) / 2 + j] = f2bf(z20[reg]); }
        { int i = 32 + i0; int j = 16 + c; if (i < 33) zr[i * (i - 1) / 2 + j] = f2bf(z21[reg]); }
    }
    if (l < 16) zr[528 + l] = 0;   // zero the K-pad for k_final
}

// ---------------- Kernel 3: out = mask * LN(Zflat @ Wl^T) via MFMA --------
// 32 rows x 512 cols per block, 512 threads (8 waves: 2M x 4N).
// Wl chunk reg-prefetch: load ks+1 while MFMAing ks.
__global__ __launch_bounds__(512) void k_final(
    const short* __restrict__ zf, const short* __restrict__ Wlb,
    const float* __restrict__ gl, const float* __restrict__ bl,
    const int* __restrict__ dims_p, float* __restrict__ out)
{
    __shared__ __align__(16) short zlds[32][552];   // 35328 B (all K at once)
    __shared__ __align__(16) short wlds[512][40];   // 40960 B (one 32-K chunk)
    __shared__ float red[32][4][2];                 //  1024 B
    const int t = threadIdx.x;
    const int wv = t >> 6;
    const int l = t & 63;
    const int g = l >> 4, c = l & 15;
    const int wm = wv >> 2;        // 0..1: row half
    const int wn = wv & 3;         // 0..3: col quarter
    const size_t r0 = (size_t)blockIdx.x * 32;

    for (int f = t; f < 32 * 68; f += 512) {
        int r = f / 68, s = f - r * 68;
        *(short8v*)(&zlds[r][s * 8]) = *(const short8v*)(zf + (r0 + r) * 544 + s * 8);
    }
    short8v wreg[4];
    #pragma unroll
    for (int j = 0; j < 4; ++j) {
        int f = t + j * 512, cc = f >> 2, part = f & 3;
        wreg[j] = *(const short8v*)(Wlb + cc * 544 + part * 8);
    }
    f32x4 acc[8];
    #pragma unroll
    for (int i = 0; i < 8; ++i) acc[i] = (f32x4){0, 0, 0, 0};
    for (int ks = 0; ks < 17; ++ks) {
        __syncthreads();                            // prev-iter wlds reads done
        #pragma unroll
        for (int j = 0; j < 4; ++j) {
            int f = t + j * 512, cc = f >> 2, part = f & 3;
            *(short8v*)(&wlds[cc][part * 8]) = wreg[j];
        }
        if (ks < 16) {
            #pragma unroll
            for (int j = 0; j < 4; ++j) {
                int f = t + j * 512, cc = f >> 2, part = f & 3;
                wreg[j] = *(const short8v*)(Wlb + cc * 544 + (ks + 1) * 32 + part * 8);
            }
        }
        __syncthreads();
        short8v af = *(const short8v*)(&zlds[wm * 16 + c][ks * 32 + g * 8]);
        #pragma unroll
        for (int nt = 0; nt < 8; ++nt) {
            short8v bf = *(const short8v*)(&wlds[wn * 128 + nt * 16 + c][g * 8]);
            acc[nt] = __builtin_amdgcn_mfma_f32_16x16x32_bf16(af, bf, acc[nt], 0, 0, 0);
        }
    }
    // LN epilogue over 512 cols per row
    #pragma unroll
    for (int reg = 0; reg < 4; ++reg) {
        float s = 0.f, q = 0.f;
        #pragma unroll
        for (int nt = 0; nt < 8; ++nt) { float v = acc[nt][reg]; s += v; q += v * v; }
        s += __shfl_xor(s, 1); q += __shfl_xor(q, 1);
        s += __shfl_xor(s, 2); q += __shfl_xor(q, 2);
        s += __shfl_xor(s, 4); q += __shfl_xor(q, 4);
        s += __shfl_xor(s, 8); q += __shfl_xor(q, 8);
        if (c == 0) { red[wm * 16 + g * 4 + reg][wn][0] = s; red[wm * 16 + g * 4 + reg][wn][1] = q; }
    }
    __syncthreads();
    const int dims = dims_p[0];
    float M[4], INV[4];
    #pragma unroll
    for (int reg = 0; reg < 4; ++reg) {
        int rr = wm * 16 + g * 4 + reg;
        float S = red[rr][0][0] + red[rr][1][0] + red[rr][2][0] + red[rr][3][0];
        float Q = red[rr][0][1] + red[rr][1][1] + red[rr][2][1] + red[rr][3][1];
        float m = S * (1.f / 512.f);
        float v = Q * (1.f / 512.f) - m * m;
        M[reg] = m; INV[reg] = rsqrtf(v + EPS);
    }
    #pragma unroll
    for (int nt = 0; nt < 8; ++nt) {
        int cc = wn * 128 + nt * 16 + c;
        float gg = (cc < dims) ? gl[cc] : 0.f;
        float bb = (cc < dims) ? bl[cc] : 0.f;
        #pragma unroll
        for (int reg = 0; reg < 4; ++reg) {
            int rr = wm * 16 + g * 4 + reg;
            out[(r0 + rr) * 512 + cc] = (acc[nt][reg] - M[reg]) * INV[reg] * gg + bb;
        }
    }
}

extern "C" void kernel_launch(void* const* d_in, const int* in_sizes, int n_in,
                              void* d_out, int out_size, void* d_ws, size_t ws_size,
                              hipStream_t stream)
{
    const float* dense  = (const float*)d_in[0];
    const float* sparse = (const float*)d_in[1];
    const float* Wd  = (const float*)d_in[2];
    const float* gd  = (const float*)d_in[3];
    const float* bd  = (const float*)d_in[4];
    const float* Ws  = (const float*)d_in[5];
    const float* gs  = (const float*)d_in[6];
    const float* bs  = (const float*)d_in[7];
    const float* Wsi = (const float*)d_in[8];
    const float* gsi = (const float*)d_in[9];
    const float* bsi = (const float*)d_in[10];
    const float* Wl  = (const float*)d_in[11];
    const float* gl  = (const float*)d_in[12];
    const float* bl  = (const float*)d_in[13];
    const int*   dims = (const int*)d_in[14];
    float* out = (float*)d_out;
    (void)n_in; (void)out_size; (void)ws_size;

    const int B = in_sizes[0] / 256;                    // 32768
    short* xbf = (short*)d_ws;                                         // B*128*2
    short* zfw = xbf + (size_t)B * 128;                                // B*544*2
    short* wsb = zfw + (size_t)B * 544;                                // 16384 B
    short* wsib = wsb + 128 * 64;                                      // 2048 B
    short* wlb  = wsib + 32 * 32;                                      // 557056 B
    short* wdb  = wlb + 512 * 544;                                     // 65536 B

    hipLaunchKernelGGL(k_prep, dim3(1088), dim3(256), 0, stream,
                       Ws, Wsi, Wl, Wd, wsb, wsib, wlb, wdb);
    hipLaunchKernelGGL(k_dense_ln, dim3(B / 32), dim3(256), 0, stream,
                       dense, wdb, gd, bd, xbf);
    hipLaunchKernelGGL(k_middle, dim3(B), dim3(64), 0, stream,
                       sparse, wsb, gs, bs, wsib, gsi, bsi, xbf, zfw);
    hipLaunchKernelGGL(k_final, dim3(B / 32), dim3(512), 0, stream,
                       zfw, wlb, gl, bl, dims, out);
}